// Round 13
// baseline (144.393 us; speedup 1.0000x reference)
//
#include <hip/hip_runtime.h>
#include <math.h>

// Canny, round 13: two-kernel split, zero cross-lane ops, zero barriers,
// 4 px/lane. K1: separable gauss -> blurred planes in d_ws (fp32).
// K2: sobel + channel-argmax + NMS + sigmoid, all lane-local via redundant
// 6-col windows. B=16, C=3, H=W=512 fixed.

typedef float v2f __attribute__((ext_vector_type(2)));
typedef float v4f __attribute__((ext_vector_type(4)));

#define PLANE (512 * 512)

// load cols C-2..C+5 of a row into d[0..7]; lz/rz: zero the outside pair
__device__ __forceinline__ void ld8(const float* __restrict__ row,
                                    bool lz, bool rz, float* d) {
    v2f L = {0.f, 0.f}, R = {0.f, 0.f};
    if (!lz) L = *(const v2f*)(row - 2);
    v4f M = *(const v4f*)row;
    if (!rz) R = *(const v2f*)(row + 4);
    d[0] = L.x; d[1] = L.y; d[2] = M.x; d[3] = M.y;
    d[4] = M.z; d[5] = M.w; d[6] = R.x; d[7] = R.y;
}

// ---------------- K1: 5x5 gaussian (zero-pad), separable ----------------
__global__ __launch_bounds__(256) void gauss_k(const float* __restrict__ x,
                                               float* __restrict__ vb)
{
    const float w0 = 0.05448868454964294f;
    const float w1 = 0.24420134200323332f;
    const float w2 = 0.4026199468942475f;
    const int lane = threadIdx.x & 63;
    const int wid  = blockIdx.x * 4 + (threadIdx.x >> 6);   // 0..3071
    const int p = wid >> 6;          // plane 0..47
    const int u = wid & 63;
    const int g = u >> 5;            // half 0/1
    const int s = u & 31;            // strip 0..31
    const int R0 = s * 16;
    const int C  = g * 256 + lane * 4;
    const bool lz = (C == 0), rz = (C == 508);
    const float* xp = x + (size_t)p * PLANE;
    float* vp = vb + (size_t)p * PLANE;

    auto hrow = [&](int r) -> v4f {
        v4f o = {0.f, 0.f, 0.f, 0.f};
        if ((unsigned)r < 512u) {                 // rows outside: zero pad
            float c[8];
            ld8(xp + r * 512 + C, lz, rz, c);
            o.x = w0 * (c[0] + c[4]) + w1 * (c[1] + c[3]) + w2 * c[2];
            o.y = w0 * (c[1] + c[5]) + w1 * (c[2] + c[4]) + w2 * c[3];
            o.z = w0 * (c[2] + c[6]) + w1 * (c[3] + c[5]) + w2 * c[4];
            o.w = w0 * (c[3] + c[7]) + w1 * (c[4] + c[6]) + w2 * c[5];
        }
        return o;
    };

    v4f h0 = hrow(R0 - 2), h1 = hrow(R0 - 1), h2 = hrow(R0), h3 = hrow(R0 + 1);
    #pragma unroll 4
    for (int m = R0; m < R0 + 16; ++m) {
        v4f h4 = hrow(m + 2);
        v4f o = w0 * (h0 + h4) + w1 * (h1 + h3) + w2 * h2;
        *(v4f*)(vp + m * 512 + C) = o;
        h0 = h1; h1 = h2; h2 = h3; h3 = h4;
    }
}

// ------- K2: sobel (edge-replicate) + argmax + NMS (zero-pad) -----------
__global__ __launch_bounds__(256) void edge_k(const float* __restrict__ vb,
                                              const int* __restrict__ lt,
                                              float* __restrict__ out)
{
    const float T1c = 0.41421356237309503f;   // tan(pi/8)
    const float T3c = 2.414213562373095f;     // tan(3pi/8)
    const int lane = threadIdx.x & 63;
    const int wid  = blockIdx.x * 4 + (threadIdx.x >> 6);   // 0..2047
    const int b = wid >> 7;          // batch
    const int u = wid & 127;
    const int g = u >> 6;            // half
    const int s = u & 63;            // strip 0..63
    const int R0 = s * 8;
    const int C  = g * 256 + lane * 4;
    const bool lz = (C == 0), rz = (C == 508);
    const float t = (float)lt[0];
    const float* vbp = vb + (size_t)(b * 3) * PLANE;

    float rA[3][8], rB[3][8], rC[3][8];   // vb rows m-1, m, m+1; cols C-2..C+5
    auto ldrow3 = [&](int r, float d[3][8]) {
        const int rc = min(max(r, 0), 511);           // row edge-replicate
        #pragma unroll
        for (int c = 0; c < 3; ++c) {
            ld8(vbp + c * PLANE + rc * 512 + C, lz, rz, d[c]);
            if (lz) d[c][1] = d[c][2];   // col -1  := col 0   (edge replicate)
            if (rz) d[c][6] = d[c][5];   // col 512 := col 511
        }
    };
    ldrow3(R0 - 2, rA);
    ldrow3(R0 - 1, rB);

    float magA[6], magB[6];   // mag rows m-2, m-1 (cols C-1..C+4)
    int dirP[4];              // dir row m-1 (cols C..C+3)
    #pragma unroll
    for (int k = 0; k < 6; ++k) { magA[k] = 0.f; magB[k] = 0.f; }
    dirP[0] = dirP[1] = dirP[2] = dirP[3] = 0;

    #pragma unroll 2
    for (int m = R0 - 1; m <= R0 + 8; ++m) {
        ldrow3(m + 1, rC);

        // sobel row m, 6 cols (C-1..C+4), channel argmax (first-max)
        float bm2[6], bgx[6], bgy[6];
        #pragma unroll
        for (int k = 0; k < 6; ++k) { bm2[k] = -1.f; bgx[k] = 0.f; bgy[k] = 0.f; }
        #pragma unroll
        for (int c = 0; c < 3; ++c) {
            float tt[8], uu[8];
            #pragma unroll
            for (int i = 0; i < 8; ++i) {
                tt[i] = rA[c][i] + 2.f * rB[c][i] + rC[c][i];
                uu[i] = rC[c][i] - rA[c][i];
            }
            #pragma unroll
            for (int k = 0; k < 6; ++k) {
                float gx = tt[k + 2] - tt[k];                 // 8x scaled
                float gy = uu[k] + 2.f * uu[k + 1] + uu[k + 2];
                float m2 = gx * gx + gy * gy;
                if (m2 > bm2[k]) { bm2[k] = m2; bgx[k] = gx; bgy[k] = gy; }
            }
        }
        float magC[6];
        const bool rowok = ((unsigned)m < 512u);
        #pragma unroll
        for (int k = 0; k < 6; ++k)     // sqrt(m2/64 + 1e-9) = 0.125*sqrt(m2+6.4e-8)
            magC[k] = rowok ? 0.125f * __builtin_amdgcn_sqrtf(bm2[k] + 6.4e-8f)
                            : 0.f;
        if (lz) magC[0] = 0.f;          // NMS zero-pad outside image
        if (rz) magC[5] = 0.f;
        int dirC[4];
        #pragma unroll
        for (int j = 0; j < 4; ++j) {   // scale cancels in gx/gy ratio
            float gx = bgx[j + 1], gy = bgy[j + 1];
            float gys = (gy == 0.f) ? 1e-9f : gy;
            float sg  = (gys > 0.f) ? 1.f : -1.f;
            float gxs = gx * sg, gya = fabsf(gys);
            float a3 = T3c * gya, a1 = T1c * gya;
            dirC[j] = (gxs >= a3 || gxs < -a3) ? 2
                    : (gxs >= a1) ? 1 : (gxs >= -a1) ? 0 : 3;
        }

        // NMS + sigmoid + store row m-1
        if (m >= R0 + 1) {
            float res[4];
            #pragma unroll
            for (int j = 0; j < 4; ++j) {
                const int k = j + 1;
                const float mm = magB[k];
                const int d = dirP[j];
                float n1 = (d == 0) ? magA[k]     : (d == 1) ? magA[k - 1]
                         : (d == 2) ? magB[k - 1] : magA[k + 1];
                float n2 = (d == 0) ? magC[k]     : (d == 1) ? magC[k + 1]
                         : (d == 2) ? magB[k + 1] : magC[k - 1];
                float ss = (mm >= n1 && mm >= n2) ? mm : 0.f;
                float v  = (ss >= t) ? ss : 1e-9f;
                res[j] = __builtin_amdgcn_rcpf(1.f + __expf(-v));
            }
            v4f o; o.x = res[0]; o.y = res[1]; o.z = res[2]; o.w = res[3];
            *(v4f*)(out + ((size_t)b * 512 + (m - 1)) * 512 + C) = o;
        }

        // rolls (renamed under unroll)
        #pragma unroll
        for (int c = 0; c < 3; ++c) {
            #pragma unroll
            for (int i = 0; i < 8; ++i) { rA[c][i] = rB[c][i]; rB[c][i] = rC[c][i]; }
        }
        #pragma unroll
        for (int k = 0; k < 6; ++k) { magA[k] = magB[k]; magB[k] = magC[k]; }
        dirP[0] = dirC[0]; dirP[1] = dirC[1]; dirP[2] = dirC[2]; dirP[3] = dirC[3];
    }
}

extern "C" void kernel_launch(void* const* d_in, const int* in_sizes, int n_in,
                              void* d_out, int out_size, void* d_ws, size_t ws_size,
                              hipStream_t stream) {
    const float* x  = (const float*)d_in[0];
    const int*   lt = (const int*)d_in[1];
    float* out = (float*)d_out;
    float* vb  = (float*)d_ws;   // 48 planes * 512*512 * 4B = 50.3 MB
    // K1: 48 planes x 2 halves x 32 strips = 3072 waves = 768 blocks
    gauss_k<<<768, dim3(256), 0, stream>>>(x, vb);
    // K2: 16 batches x 2 halves x 64 strips = 2048 waves = 512 blocks
    edge_k<<<512, dim3(256), 0, stream>>>(vb, lt, out);
}